// Round 2
// baseline (344.522 us; speedup 1.0000x reference)
//
#include <hip/hip_runtime.h>

typedef _Float16 half_t;
typedef __attribute__((ext_vector_type(8))) _Float16 f16x8;   // 8 fp16 = 4 VGPRs
typedef __attribute__((ext_vector_type(4))) _Float16 f16x4;
typedef __attribute__((ext_vector_type(4))) float f32x4;
typedef __attribute__((ext_vector_type(4))) float float4v;

__device__ __forceinline__ void gload_lds16(const void* g, void* l) {
  __builtin_amdgcn_global_load_lds(
      (const __attribute__((address_space(1))) void*)g,
      (__attribute__((address_space(3))) void*)l, 16, 0, 0);
}

// ---------------------------------------------------------------------------
// C = A (MxK, row-major fp16) * B (KxN) given Bt = B^T (NxK row-major fp16)
// MODE 0: C = acc ; MODE 1: C = (acc + bias[col]) * alpha
// MODE 2: C = acc + rowscale[row] * bias[col]
// Per-z batch: ptr += z * s{A,B,C} (element strides).
// ---------------------------------------------------------------------------
template<int BM, int BN, int WM, int WN, int OUTF16, int MODE>
__global__ __launch_bounds__(256, 2)
void gemm_bt(const half_t* __restrict__ A, const half_t* __restrict__ Bt,
             void* __restrict__ Cv, const float* __restrict__ bias,
             const float* __restrict__ rowscale,
             int M, int N, int K, int lda, int ldb, int ldc, float alpha,
             long sA, long sB, long sC)
{
  constexpr int FM = WM / 16, FN = WN / 16, CW = BN / WN;
  __shared__ __attribute__((aligned(16))) half_t As[BM * 32];
  __shared__ __attribute__((aligned(16))) half_t Bs[BN * 32];

  const int tid = threadIdx.x, w = tid >> 6, lane = tid & 63;
  const int wr = w / CW, wc = w % CW;
  const int z = blockIdx.z;
  const half_t* Ab = A + (long)z * sA;
  const half_t* Bb = Bt + (long)z * sB;
  const int m0 = blockIdx.x * BM, n0 = blockIdx.y * BN;
  const int g = lane >> 4, cc = lane & 15;
  const int srow = lane >> 2, scol = (lane & 3) * 8;   // staging lane map

  const f32x4 zero = {0.f, 0.f, 0.f, 0.f};
  f32x4 acc[FM][FN];
#pragma unroll
  for (int i = 0; i < FM; ++i)
#pragma unroll
    for (int j = 0; j < FN; ++j) acc[i][j] = zero;

  for (int kt = 0; kt < K; kt += 32) {
#pragma unroll
    for (int j = 0; j < BM / 64; ++j) {
      const int bi = w * (BM / 64) + j;
      gload_lds16(Ab + (long)(m0 + bi * 16 + srow) * lda + kt + scol, &As[bi * 512]);
    }
#pragma unroll
    for (int j = 0; j < BN / 64; ++j) {
      const int bi = w * (BN / 64) + j;
      gload_lds16(Bb + (long)(n0 + bi * 16 + srow) * ldb + kt + scol, &Bs[bi * 512]);
    }
    __syncthreads();   // drains vmcnt -> staged data visible

    f16x8 af[FM], bf[FN];
#pragma unroll
    for (int i = 0; i < FM; ++i)
      af[i] = *(const f16x8*)&As[(wr * WM + i * 16 + cc) * 32 + g * 8];
#pragma unroll
    for (int j = 0; j < FN; ++j)
      bf[j] = *(const f16x8*)&Bs[(wc * WN + j * 16 + cc) * 32 + g * 8];
#pragma unroll
    for (int i = 0; i < FM; ++i)
#pragma unroll
      for (int j = 0; j < FN; ++j)
        acc[i][j] = __builtin_amdgcn_mfma_f32_16x16x32_f16(af[i], bf[j], acc[i][j], 0, 0, 0);
    __syncthreads();   // before next-tile staging overwrites LDS
  }

  const long coff = (long)z * sC;
#pragma unroll
  for (int i = 0; i < FM; ++i)
#pragma unroll
    for (int j = 0; j < FN; ++j)
#pragma unroll
      for (int r = 0; r < 4; ++r) {
        const int row = m0 + wr * WM + i * 16 + g * 4 + r;   // C/D: row=(l>>4)*4+reg
        const int col = n0 + wc * WN + j * 16 + cc;          //      col=l&15
        float v = acc[i][j][r];
        if (MODE == 1) v = (v + bias[col]) * alpha;
        if (MODE == 2) v = v + rowscale[row] * bias[col];
        if (OUTF16) ((half_t*)Cv)[coff + (long)row * ldc + col] = (half_t)v;
        else        ((float*)Cv)[coff + (long)row * ldc + col] = v;
      }
}

// ---------------------------------------------------------------------------
// Fused attention: per (b,h, 128 q-rows): logits = q*kE^T (red=64), softmax
// over 256 compressed keys (in-register, 16-lane shuffle reduce),
// P relayout via per-wave private LDS chunks, PV accumulate, write out_pre.
// ---------------------------------------------------------------------------
__global__ __launch_bounds__(256, 2)
void attn_fused(const half_t* __restrict__ q, const half_t* __restrict__ kE,
                const half_t* __restrict__ vFt, half_t* __restrict__ outp, int L)
{
  __shared__ __attribute__((aligned(16))) half_t P[4][32 * 80];  // per-wave P chunk
  const int tid = threadIdx.x, w = tid >> 6, lane = tid & 63;
  const int g = lane >> 4, c = lane & 15;
  const int l0 = blockIdx.x * 128, h = blockIdx.y, b = blockIdx.z;

  const half_t* qb = q + ((long)b * L + l0 + w * 32) * 1024 + h * 64;
  const half_t* keb = kE + (long)b * 262144 + h * 64;
  const half_t* vb  = vFt + (long)b * 262144 + (long)h * 64 * 256;
  half_t* ob = outp + ((long)b * L + l0 + w * 32) * 1024 + h * 64;

  // q fragments (A-operand), rows = wave's 32 q-rows
  f16x8 qa[2][2];
#pragma unroll
  for (int fi = 0; fi < 2; ++fi)
#pragma unroll
    for (int ks = 0; ks < 2; ++ks)
      qa[fi][ks] = *(const f16x8*)(qb + (long)(fi * 16 + c) * 1024 + ks * 32 + g * 8);

  const f32x4 zero = {0.f, 0.f, 0.f, 0.f};
  f32x4 s[2][16];
#pragma unroll
  for (int fi = 0; fi < 2; ++fi)
#pragma unroll
    for (int fj = 0; fj < 16; ++fj) s[fi][fj] = zero;

  // QK^T: 256 kk cols, red = 64
#pragma unroll
  for (int fj = 0; fj < 16; ++fj) {
    f16x8 b0 = *(const f16x8*)(keb + (long)(fj * 16 + c) * 1024 + g * 8);
    f16x8 b1 = *(const f16x8*)(keb + (long)(fj * 16 + c) * 1024 + 32 + g * 8);
#pragma unroll
    for (int fi = 0; fi < 2; ++fi) {
      s[fi][fj] = __builtin_amdgcn_mfma_f32_16x16x32_f16(qa[fi][0], b0, s[fi][fj], 0, 0, 0);
      s[fi][fj] = __builtin_amdgcn_mfma_f32_16x16x32_f16(qa[fi][1], b1, s[fi][fj], 0, 0, 0);
    }
  }

  // softmax: row = w*32 + fi*16 + g*4 + r; its 256 vals live in 16 lanes x 16 frags
#pragma unroll
  for (int fi = 0; fi < 2; ++fi)
#pragma unroll
    for (int r = 0; r < 4; ++r) {
      float m = -3.0e38f;
#pragma unroll
      for (int fj = 0; fj < 16; ++fj) m = fmaxf(m, s[fi][fj][r]);
      m = fmaxf(m, __shfl_xor(m, 1));
      m = fmaxf(m, __shfl_xor(m, 2));
      m = fmaxf(m, __shfl_xor(m, 4));
      m = fmaxf(m, __shfl_xor(m, 8));
      float sum = 0.f;
#pragma unroll
      for (int fj = 0; fj < 16; ++fj) {
        float e = __expf(s[fi][fj][r] - m);
        s[fi][fj][r] = e; sum += e;
      }
      sum += __shfl_xor(sum, 1);
      sum += __shfl_xor(sum, 2);
      sum += __shfl_xor(sum, 4);
      sum += __shfl_xor(sum, 8);
      const float inv = 1.0f / sum;
#pragma unroll
      for (int fj = 0; fj < 16; ++fj) s[fi][fj][r] *= inv;
    }

  f32x4 o[2][4];
#pragma unroll
  for (int fi = 0; fi < 2; ++fi)
#pragma unroll
    for (int fj = 0; fj < 4; ++fj) o[fi][fj] = zero;

  // PV over kk=256 in 4 chunks of 64: D-layout P -> LDS -> A-layout fragments
  half_t* pb = &P[w][0];
#pragma unroll
  for (int ch = 0; ch < 4; ++ch) {
#pragma unroll
    for (int fi = 0; fi < 2; ++fi)
#pragma unroll
      for (int fjl = 0; fjl < 4; ++fjl)
#pragma unroll
        for (int r = 0; r < 4; ++r)
          pb[(fi * 16 + g * 4 + r) * 80 + fjl * 16 + c] = (half_t)s[fi][ch * 4 + fjl][r];
    f16x8 pa[2][2];
#pragma unroll
    for (int fi = 0; fi < 2; ++fi)
#pragma unroll
      for (int ks = 0; ks < 2; ++ks)
        pa[fi][ks] = *(const f16x8*)&pb[(fi * 16 + c) * 80 + ks * 32 + g * 8];
#pragma unroll
    for (int fjv = 0; fjv < 4; ++fjv) {
      f16x8 v0 = *(const f16x8*)(vb + (long)(fjv * 16 + c) * 256 + ch * 64 + g * 8);
      f16x8 v1 = *(const f16x8*)(vb + (long)(fjv * 16 + c) * 256 + ch * 64 + 32 + g * 8);
#pragma unroll
      for (int fi = 0; fi < 2; ++fi) {
        o[fi][fjv] = __builtin_amdgcn_mfma_f32_16x16x32_f16(pa[fi][0], v0, o[fi][fjv], 0, 0, 0);
        o[fi][fjv] = __builtin_amdgcn_mfma_f32_16x16x32_f16(pa[fi][1], v1, o[fi][fjv], 0, 0, 0);
      }
    }
  }

#pragma unroll
  for (int fi = 0; fi < 2; ++fi)
#pragma unroll
    for (int fjv = 0; fjv < 4; ++fjv)
#pragma unroll
      for (int r = 0; r < 4; ++r)
        ob[(long)(fi * 16 + g * 4 + r) * 1024 + fjv * 16 + c] = (half_t)o[fi][fjv][r];
}

// ---------------------------------------------------------------------------
// helpers: fp32->fp16 convert, tiled transpose (fp32 in -> fp16 out), colsum
// ---------------------------------------------------------------------------
__global__ void cvt_f16(const float* __restrict__ in, half_t* __restrict__ out, long n) {
  long i = ((long)blockIdx.x * 256 + threadIdx.x) * 4;
  if (i >= n) return;
  float4v v = *(const float4v*)(in + i);
  f16x4 o;
#pragma unroll
  for (int j = 0; j < 4; ++j) o[j] = (half_t)v[j];
  *(f16x4*)(out + i) = o;
}

__global__ void transpose_f32_f16(const float* __restrict__ in, half_t* __restrict__ out,
                                  int R, int C, long inB, long outB) {
  __shared__ float t[32][33];
  const float* ip = in + (long)blockIdx.z * inB;
  half_t* op = out + (long)blockIdx.z * outB;
  const int cx = blockIdx.x * 32 + threadIdx.x;
  const int r0 = blockIdx.y * 32;
#pragma unroll
  for (int j = 0; j < 4; ++j)
    t[threadIdx.y + 8 * j][threadIdx.x] = ip[(long)(r0 + threadIdx.y + 8 * j) * C + cx];
  __syncthreads();
  const int rx = r0 + threadIdx.x;
  const int cy = blockIdx.x * 32 + threadIdx.y;
#pragma unroll
  for (int j = 0; j < 4; ++j)
    op[(long)(cy + 8 * j) * R + rx] = (half_t)t[threadIdx.x][threadIdx.y + 8 * j];
}

__global__ void colsum(const float* __restrict__ in, float* __restrict__ s) {
  const int col = threadIdx.x;          // 256 cols
  const int r0 = blockIdx.x * 128;
  float a = 0.f;
  for (int r = 0; r < 128; ++r) a += in[(long)(r0 + r) * 256 + col];
  atomicAdd(&s[col], a);
}

// ---------------------------------------------------------------------------
extern "C" void kernel_launch(void* const* d_in, const int* in_sizes, int n_in,
                              void* d_out, int out_size, void* d_ws, size_t ws_size,
                              hipStream_t stream)
{
  const float* x  = (const float*)d_in[0];
  const float* Wq = (const float*)d_in[1];
  const float* bq = (const float*)d_in[2];
  const float* Wk = (const float*)d_in[3];
  const float* bk = (const float*)d_in[4];
  const float* Wv = (const float*)d_in[5];
  const float* bv = (const float*)d_in[6];
  const float* E  = (const float*)d_in[7];
  const float* F  = (const float*)d_in[8];
  const float* Wo = (const float*)d_in[9];
  const float* bo = (const float*)d_in[10];
  float* out = (float*)d_out;

  char* ws = (char*)d_ws;
  half_t* xhf  = (half_t*)(ws);                 // 33.5MB; later reused as out_pre
  half_t* xT   = (half_t*)(ws + 33554432);      // 33.5MB (dead after xEF gemm)
  half_t* qhf  = (half_t*)(ws + 67108864);      // 33.5MB
  half_t* Wqt  = (half_t*)(ws + 100663296);
  half_t* Wkt  = Wqt + 1048576;
  half_t* Wvt  = Wkt + 1048576;
  half_t* Wot  = Wvt + 1048576;
  half_t* EFt  = (half_t*)(ws + 109051904);     // [512][4096]: E^T on top of F^T
  half_t* xEF  = (half_t*)(ws + 113246208);     // per b: [512][1024] = [xE; xF]
  half_t* kEb  = (half_t*)(ws + 117440512);     // per b: [256][1024]
  half_t* vFtb = (half_t*)(ws + 119537664);     // per b: [1024][256]
  float*  sEF  = (float*)(ws + 121634816);      // sE[256], sF[256]
  half_t* outp = xhf;                           // out_pre overlays x_f16

  hipMemsetAsync(sEF, 0, 2048, stream);
  cvt_f16<<<16384, 256, 0, stream>>>(x, xhf, 16777216L);
  dim3 tb(32, 8);
  transpose_f32_f16<<<dim3(32, 32, 1), tb, 0, stream>>>(Wq, Wqt, 1024, 1024, 0, 0);
  transpose_f32_f16<<<dim3(32, 32, 1), tb, 0, stream>>>(Wk, Wkt, 1024, 1024, 0, 0);
  transpose_f32_f16<<<dim3(32, 32, 1), tb, 0, stream>>>(Wv, Wvt, 1024, 1024, 0, 0);
  transpose_f32_f16<<<dim3(32, 32, 1), tb, 0, stream>>>(Wo, Wot, 1024, 1024, 0, 0);
  transpose_f32_f16<<<dim3(8, 128, 1), tb, 0, stream>>>(E, EFt, 4096, 256, 0, 0);
  transpose_f32_f16<<<dim3(8, 128, 1), tb, 0, stream>>>(F, EFt + 1048576, 4096, 256, 0, 0);
  transpose_f32_f16<<<dim3(32, 128, 4), tb, 0, stream>>>(x, xT, 4096, 1024, 4194304, 4194304);
  colsum<<<32, 256, 0, stream>>>(E, sEF);
  colsum<<<32, 256, 0, stream>>>(F, sEF + 256);

  // q = (x@Wq + bq) * hd^-0.5  -> fp16 [16384][1024]
  gemm_bt<128,128,64,64,1,1><<<dim3(128, 8, 1), 256, 0, stream>>>(
      xhf, Wqt, qhf, bq, nullptr, 16384, 1024, 1024, 1024, 1024, 1024, 0.125f, 0, 0, 0);
  // xEF[b] = [E^T; F^T] @ x_b   (M=512, N=1024, K=4096)
  gemm_bt<128,128,64,64,1,0><<<dim3(4, 8, 4), 256, 0, stream>>>(
      EFt, xT, xEF, nullptr, nullptr, 512, 1024, 4096, 4096, 4096, 1024, 1.f,
      0, 4194304, 524288);
  // kE[b] = xE_b @ Wk + sE*bk   (M=256, N=1024, K=1024)
  gemm_bt<128,128,64,64,1,2><<<dim3(2, 8, 4), 256, 0, stream>>>(
      xEF, Wkt, kEb, bk, sEF, 256, 1024, 1024, 1024, 1024, 1024, 1.f,
      524288, 0, 262144);
  // vFt[b] = Wv^T @ xF_b^T + bv*sF  (M=1024, N=256, K=1024)
  gemm_bt<128,128,64,64,1,2><<<dim3(8, 2, 4), 256, 0, stream>>>(
      Wvt, xEF + 262144, vFtb, sEF + 256, bv, 1024, 256, 1024, 1024, 1024, 256, 1.f,
      0, 524288, 262144);
  // fused qk^T -> softmax -> PV   (writes out_pre fp16 [b][l][h*64+d])
  attn_fused<<<dim3(32, 16, 4), 256, 0, stream>>>(qhf, kEb, vFtb, outp, 4096);
  // out = out_pre @ Wo + bo  (fp32)
  gemm_bt<128,128,64,64,0,1><<<dim3(128, 8, 1), 256, 0, stream>>>(
      outp, Wot, (void*)out, bo, nullptr, 16384, 1024, 1024, 1024, 1024, 1024, 1.f, 0, 0, 0);
  (void)in_sizes; (void)n_in; (void)out_size; (void)ws_size;
}

// Round 3
// 336.366 us; speedup vs baseline: 1.0242x; 1.0242x over previous
//
#include <hip/hip_runtime.h>

typedef _Float16 half_t;
typedef __attribute__((ext_vector_type(8))) _Float16 f16x8;   // 8 fp16 = 4 VGPRs
typedef __attribute__((ext_vector_type(4))) _Float16 f16x4;
typedef __attribute__((ext_vector_type(4))) float f32x4;
typedef __attribute__((ext_vector_type(4))) float float4v;

__device__ __forceinline__ void gload_lds16(const void* g, void* l) {
  __builtin_amdgcn_global_load_lds(
      (const __attribute__((address_space(1))) void*)g,
      (__attribute__((address_space(3))) void*)l, 16, 0, 0);
}

// ---------------------------------------------------------------------------
// C = A (MxK, row-major fp16) * B (KxN) given Bt = B^T (NxK row-major fp16)
// MODE 0: C = acc ; MODE 1: C = (acc + bias[col]) * alpha
// MODE 2: C = acc + rowscale[row] * bias[col]
// MODE 3: atomicAdd f32 (split-K accumulate), no bias
// SK: split-K factor; blockIdx.z = batch * SK + kslice.
// ---------------------------------------------------------------------------
template<int BM, int BN, int WM, int WN, int OUTF16, int MODE, int SK>
__global__ __launch_bounds__(256, 2)
void gemm_bt(const half_t* __restrict__ A, const half_t* __restrict__ Bt,
             void* __restrict__ Cv, const float* __restrict__ bias,
             const float* __restrict__ rowscale,
             int M, int N, int K, int lda, int ldb, int ldc, float alpha,
             long sA, long sB, long sC)
{
  constexpr int FM = WM / 16, FN = WN / 16, CW = BN / WN;
  __shared__ __attribute__((aligned(16))) half_t As[BM * 32];
  __shared__ __attribute__((aligned(16))) half_t Bs[BN * 32];

  const int tid = threadIdx.x, w = tid >> 6, lane = tid & 63;
  const int wr = w / CW, wc = w % CW;
  const int z = blockIdx.z / SK, ks = blockIdx.z % SK;
  const half_t* Ab = A + (long)z * sA;
  const half_t* Bb = Bt + (long)z * sB;
  const int m0 = blockIdx.x * BM, n0 = blockIdx.y * BN;
  const int g = lane >> 4, cc = lane & 15;
  const int srow = lane >> 2, scol = (lane & 3) * 8;   // staging lane map

  const f32x4 zero = {0.f, 0.f, 0.f, 0.f};
  f32x4 acc[FM][FN];
#pragma unroll
  for (int i = 0; i < FM; ++i)
#pragma unroll
    for (int j = 0; j < FN; ++j) acc[i][j] = zero;

  const int kchunk = K / SK;
  for (int kt = ks * kchunk; kt < (ks + 1) * kchunk; kt += 32) {
#pragma unroll
    for (int j = 0; j < BM / 64; ++j) {
      const int bi = w * (BM / 64) + j;
      gload_lds16(Ab + (long)(m0 + bi * 16 + srow) * lda + kt + scol, &As[bi * 512]);
    }
#pragma unroll
    for (int j = 0; j < BN / 64; ++j) {
      const int bi = w * (BN / 64) + j;
      gload_lds16(Bb + (long)(n0 + bi * 16 + srow) * ldb + kt + scol, &Bs[bi * 512]);
    }
    __syncthreads();   // drains vmcnt -> staged data visible

    f16x8 af[FM], bf[FN];
#pragma unroll
    for (int i = 0; i < FM; ++i)
      af[i] = *(const f16x8*)&As[(wr * WM + i * 16 + cc) * 32 + g * 8];
#pragma unroll
    for (int j = 0; j < FN; ++j)
      bf[j] = *(const f16x8*)&Bs[(wc * WN + j * 16 + cc) * 32 + g * 8];
#pragma unroll
    for (int i = 0; i < FM; ++i)
#pragma unroll
      for (int j = 0; j < FN; ++j)
        acc[i][j] = __builtin_amdgcn_mfma_f32_16x16x32_f16(af[i], bf[j], acc[i][j], 0, 0, 0);
    __syncthreads();   // before next-tile staging overwrites LDS
  }

  const long coff = (long)z * sC;
#pragma unroll
  for (int i = 0; i < FM; ++i)
#pragma unroll
    for (int j = 0; j < FN; ++j)
#pragma unroll
      for (int r = 0; r < 4; ++r) {
        const int row = m0 + wr * WM + i * 16 + g * 4 + r;   // C/D: row=(l>>4)*4+reg
        const int col = n0 + wc * WN + j * 16 + cc;          //      col=l&15
        float v = acc[i][j][r];
        if (MODE == 1) v = (v + bias[col]) * alpha;
        if (MODE == 2) v = v + rowscale[row] * bias[col];
        if (MODE == 3) {
          atomicAdd(&((float*)Cv)[coff + (long)row * ldc + col], v);
        } else {
          if (OUTF16) ((half_t*)Cv)[coff + (long)row * ldc + col] = (half_t)v;
          else        ((float*)Cv)[coff + (long)row * ldc + col] = v;
        }
      }
}

// ---------------------------------------------------------------------------
// Fused attention: per (b,h, 128 q-rows): logits = q*kE^T (red=64), softmax
// over 256 compressed keys (in-register, 16-lane shuffle reduce),
// P relayout via per-wave private LDS chunks, PV accumulate, write out_pre.
// ---------------------------------------------------------------------------
__global__ __launch_bounds__(256, 2)
void attn_fused(const half_t* __restrict__ q, const half_t* __restrict__ kE,
                const half_t* __restrict__ vFt, half_t* __restrict__ outp, int L)
{
  __shared__ __attribute__((aligned(16))) half_t P[4][32 * 80];  // per-wave P chunk
  const int tid = threadIdx.x, w = tid >> 6, lane = tid & 63;
  const int g = lane >> 4, c = lane & 15;
  const int l0 = blockIdx.x * 128, h = blockIdx.y, b = blockIdx.z;

  const half_t* qb = q + ((long)b * L + l0 + w * 32) * 1024 + h * 64;
  const half_t* keb = kE + (long)b * 262144 + h * 64;
  const half_t* vb  = vFt + (long)b * 262144 + (long)h * 64 * 256;
  half_t* ob = outp + ((long)b * L + l0 + w * 32) * 1024 + h * 64;

  // q fragments (A-operand), rows = wave's 32 q-rows
  f16x8 qa[2][2];
#pragma unroll
  for (int fi = 0; fi < 2; ++fi)
#pragma unroll
    for (int ks = 0; ks < 2; ++ks)
      qa[fi][ks] = *(const f16x8*)(qb + (long)(fi * 16 + c) * 1024 + ks * 32 + g * 8);

  const f32x4 zero = {0.f, 0.f, 0.f, 0.f};
  f32x4 s[2][16];
#pragma unroll
  for (int fi = 0; fi < 2; ++fi)
#pragma unroll
    for (int fj = 0; fj < 16; ++fj) s[fi][fj] = zero;

  // QK^T: 256 kk cols, red = 64
#pragma unroll
  for (int fj = 0; fj < 16; ++fj) {
    f16x8 b0 = *(const f16x8*)(keb + (long)(fj * 16 + c) * 1024 + g * 8);
    f16x8 b1 = *(const f16x8*)(keb + (long)(fj * 16 + c) * 1024 + 32 + g * 8);
#pragma unroll
    for (int fi = 0; fi < 2; ++fi) {
      s[fi][fj] = __builtin_amdgcn_mfma_f32_16x16x32_f16(qa[fi][0], b0, s[fi][fj], 0, 0, 0);
      s[fi][fj] = __builtin_amdgcn_mfma_f32_16x16x32_f16(qa[fi][1], b1, s[fi][fj], 0, 0, 0);
    }
  }

  // softmax: row = w*32 + fi*16 + g*4 + r; its 256 vals live in 16 lanes x 16 frags
#pragma unroll
  for (int fi = 0; fi < 2; ++fi)
#pragma unroll
    for (int r = 0; r < 4; ++r) {
      float m = -3.0e38f;
#pragma unroll
      for (int fj = 0; fj < 16; ++fj) m = fmaxf(m, s[fi][fj][r]);
      m = fmaxf(m, __shfl_xor(m, 1));
      m = fmaxf(m, __shfl_xor(m, 2));
      m = fmaxf(m, __shfl_xor(m, 4));
      m = fmaxf(m, __shfl_xor(m, 8));
      float sum = 0.f;
#pragma unroll
      for (int fj = 0; fj < 16; ++fj) {
        float e = __expf(s[fi][fj][r] - m);
        s[fi][fj][r] = e; sum += e;
      }
      sum += __shfl_xor(sum, 1);
      sum += __shfl_xor(sum, 2);
      sum += __shfl_xor(sum, 4);
      sum += __shfl_xor(sum, 8);
      const float inv = 1.0f / sum;
#pragma unroll
      for (int fj = 0; fj < 16; ++fj) s[fi][fj][r] *= inv;
    }

  f32x4 o[2][4];
#pragma unroll
  for (int fi = 0; fi < 2; ++fi)
#pragma unroll
    for (int fj = 0; fj < 4; ++fj) o[fi][fj] = zero;

  // PV over kk=256 in 4 chunks of 64: D-layout P -> LDS -> A-layout fragments
  half_t* pb = &P[w][0];
#pragma unroll
  for (int ch = 0; ch < 4; ++ch) {
#pragma unroll
    for (int fi = 0; fi < 2; ++fi)
#pragma unroll
      for (int fjl = 0; fjl < 4; ++fjl)
#pragma unroll
        for (int r = 0; r < 4; ++r)
          pb[(fi * 16 + g * 4 + r) * 80 + fjl * 16 + c] = (half_t)s[fi][ch * 4 + fjl][r];
    f16x8 pa[2][2];
#pragma unroll
    for (int fi = 0; fi < 2; ++fi)
#pragma unroll
      for (int ks = 0; ks < 2; ++ks)
        pa[fi][ks] = *(const f16x8*)&pb[(fi * 16 + c) * 80 + ks * 32 + g * 8];
#pragma unroll
    for (int fjv = 0; fjv < 4; ++fjv) {
      f16x8 v0 = *(const f16x8*)(vb + (long)(fjv * 16 + c) * 256 + ch * 64 + g * 8);
      f16x8 v1 = *(const f16x8*)(vb + (long)(fjv * 16 + c) * 256 + ch * 64 + 32 + g * 8);
#pragma unroll
      for (int fi = 0; fi < 2; ++fi) {
        o[fi][fjv] = __builtin_amdgcn_mfma_f32_16x16x32_f16(pa[fi][0], v0, o[fi][fjv], 0, 0, 0);
        o[fi][fjv] = __builtin_amdgcn_mfma_f32_16x16x32_f16(pa[fi][1], v1, o[fi][fjv], 0, 0, 0);
      }
    }
  }

#pragma unroll
  for (int fi = 0; fi < 2; ++fi)
#pragma unroll
    for (int fjv = 0; fjv < 4; ++fjv)
#pragma unroll
      for (int r = 0; r < 4; ++r)
        ob[(long)(fi * 16 + g * 4 + r) * 1024 + fjv * 16 + c] = (half_t)o[fi][fjv][r];
}

// ---------------------------------------------------------------------------
// helpers
// ---------------------------------------------------------------------------
__global__ void cvt_f16(const float* __restrict__ in, half_t* __restrict__ out, long n) {
  long i = ((long)blockIdx.x * 256 + threadIdx.x) * 4;
  if (i >= n) return;
  float4v v = *(const float4v*)(in + i);
  f16x4 o;
#pragma unroll
  for (int j = 0; j < 4; ++j) o[j] = (half_t)v[j];
  *(f16x4*)(out + i) = o;
}

// x [4][4096][1024] f32 -> xhf fp16 (same layout) AND xT [4][1024][4096] fp16
__global__ void xpass(const float* __restrict__ x, half_t* __restrict__ xhf,
                      half_t* __restrict__ xT) {
  __shared__ float t[32][33];
  const int b = blockIdx.z, d0 = blockIdx.x * 32, l0 = blockIdx.y * 32;
  const int tx = threadIdx.x, ty = threadIdx.y;
  const float* ip = x + ((long)b * 4096 + l0) * 1024 + d0;
  half_t* oh = xhf + ((long)b * 4096 + l0) * 1024 + d0;
#pragma unroll
  for (int j = 0; j < 4; ++j) {
    float v = ip[(long)(ty + 8 * j) * 1024 + tx];
    t[ty + 8 * j][tx] = v;
    oh[(long)(ty + 8 * j) * 1024 + tx] = (half_t)v;
  }
  __syncthreads();
  half_t* ot = xT + ((long)b * 1024 + d0) * 4096 + l0;
#pragma unroll
  for (int j = 0; j < 4; ++j)
    ot[(long)(ty + 8 * j) * 4096 + tx] = (half_t)t[tx][ty + 8 * j];
}

// E [4096][256] f32 -> E^T [256][4096] fp16, plus colsum(E) -> ssum[256]
__global__ void efpass(const float* __restrict__ in, half_t* __restrict__ outT,
                       float* __restrict__ ssum) {
  __shared__ float t[32][33];
  __shared__ float ps[8][32];
  const int k0 = blockIdx.x * 32, l0 = blockIdx.y * 32;
  const int tx = threadIdx.x, ty = threadIdx.y;
  float p = 0.f;
#pragma unroll
  for (int j = 0; j < 4; ++j) {
    float v = in[(long)(l0 + ty + 8 * j) * 256 + k0 + tx];
    t[ty + 8 * j][tx] = v; p += v;
  }
  ps[ty][tx] = p;
  __syncthreads();
  if (ty == 0) {
    float a = 0.f;
#pragma unroll
    for (int r = 0; r < 8; ++r) a += ps[r][tx];
    atomicAdd(&ssum[k0 + tx], a);
  }
#pragma unroll
  for (int j = 0; j < 4; ++j)
    outT[(long)(k0 + ty + 8 * j) * 4096 + l0 + tx] = (half_t)t[tx][ty + 8 * j];
}

__global__ void transpose_f32_f16(const float* __restrict__ in, half_t* __restrict__ out,
                                  int R, int C) {
  __shared__ float t[32][33];
  const int cx = blockIdx.x * 32 + threadIdx.x;
  const int r0 = blockIdx.y * 32;
#pragma unroll
  for (int j = 0; j < 4; ++j)
    t[threadIdx.y + 8 * j][threadIdx.x] = in[(long)(r0 + threadIdx.y + 8 * j) * C + cx];
  __syncthreads();
  const int rx = r0 + threadIdx.x;
  const int cy = blockIdx.x * 32 + threadIdx.y;
#pragma unroll
  for (int j = 0; j < 4; ++j)
    out[(long)(cy + 8 * j) * R + rx] = (half_t)t[threadIdx.x][threadIdx.y + 8 * j];
}

// ---------------------------------------------------------------------------
extern "C" void kernel_launch(void* const* d_in, const int* in_sizes, int n_in,
                              void* d_out, int out_size, void* d_ws, size_t ws_size,
                              hipStream_t stream)
{
  const float* x  = (const float*)d_in[0];
  const float* Wq = (const float*)d_in[1];
  const float* bq = (const float*)d_in[2];
  const float* Wk = (const float*)d_in[3];
  const float* bk = (const float*)d_in[4];
  const float* Wv = (const float*)d_in[5];
  const float* bv = (const float*)d_in[6];
  const float* E  = (const float*)d_in[7];
  const float* F  = (const float*)d_in[8];
  const float* Wo = (const float*)d_in[9];
  const float* bo = (const float*)d_in[10];
  float* out = (float*)d_out;

  char* ws = (char*)d_ws;
  half_t* xhf  = (half_t*)(ws);                 // 33.5MB; later reused as out_pre
  half_t* xT   = (half_t*)(ws + 33554432);      // 33.5MB (dead after xEF gemm)
  half_t* qhf  = (half_t*)(ws + 67108864);      // 33.5MB
  half_t* Wqt  = (half_t*)(ws + 100663296);
  half_t* Wkt  = Wqt + 1048576;
  half_t* Wvt  = Wkt + 1048576;
  half_t* Wot  = Wvt + 1048576;
  half_t* EFt  = (half_t*)(ws + 109051904);     // [512][4096]: E^T on top of F^T
  half_t* xEF  = (half_t*)(ws + 113246208);     // per b: [512][1024] = [xE; xF]
  half_t* kEb  = (half_t*)(ws + 117440512);     // per b: [256][1024]
  half_t* vFtb = (half_t*)(ws + 119537664);     // per b: [1024][256]
  float*  sEF  = (float*)(ws + 121634816);      // sE[256], sF[256]
  half_t* outp = xhf;                           // out_pre overlays x_f16
  float*  xEFf = (float*)d_out;                 // 8MB split-K scratch in d_out head
                                                // (fully overwritten by final GEMM)

  hipMemsetAsync(sEF, 0, 2048, stream);
  hipMemsetAsync(xEFf, 0, 8388608, stream);
  dim3 tb(32, 8);
  xpass<<<dim3(32, 128, 4), tb, 0, stream>>>(x, xhf, xT);
  efpass<<<dim3(8, 128, 1), tb, 0, stream>>>(E, EFt, sEF);
  efpass<<<dim3(8, 128, 1), tb, 0, stream>>>(F, EFt + 1048576, sEF + 256);
  transpose_f32_f16<<<dim3(32, 32, 1), tb, 0, stream>>>(Wq, Wqt, 1024, 1024);
  transpose_f32_f16<<<dim3(32, 32, 1), tb, 0, stream>>>(Wk, Wkt, 1024, 1024);
  transpose_f32_f16<<<dim3(32, 32, 1), tb, 0, stream>>>(Wv, Wvt, 1024, 1024);
  transpose_f32_f16<<<dim3(32, 32, 1), tb, 0, stream>>>(Wo, Wot, 1024, 1024);

  // xEFf[b] = [E^T; F^T] @ x_b  (M=512, N=1024, K=4096) split-K=8, f32 atomics
  gemm_bt<128,128,64,64,0,3,8><<<dim3(4, 8, 32), 256, 0, stream>>>(
      EFt, xT, (void*)xEFf, nullptr, nullptr, 512, 1024, 4096, 4096, 4096, 1024, 1.f,
      0, 4194304, 524288);
  cvt_f16<<<2048, 256, 0, stream>>>(xEFf, xEF, 2097152L);

  // q = (x@Wq + bq) * hd^-0.5  -> fp16 [16384][1024]
  gemm_bt<128,128,64,64,1,1,1><<<dim3(128, 8, 1), 256, 0, stream>>>(
      xhf, Wqt, qhf, bq, nullptr, 16384, 1024, 1024, 1024, 1024, 1024, 0.125f, 0, 0, 0);
  // kE[b] = xE_b @ Wk + sE*bk   (M=256, N=1024, K=1024)
  gemm_bt<128,128,64,64,1,2,1><<<dim3(2, 8, 4), 256, 0, stream>>>(
      xEF, Wkt, kEb, bk, sEF, 256, 1024, 1024, 1024, 1024, 1024, 1.f,
      524288, 0, 262144);
  // vFt[b] = Wv^T @ xF_b^T + bv*sF  (M=1024, N=256, K=1024)
  gemm_bt<128,128,64,64,1,2,1><<<dim3(8, 2, 4), 256, 0, stream>>>(
      Wvt, xEF + 262144, vFtb, sEF + 256, bv, 1024, 256, 1024, 1024, 1024, 256, 1.f,
      0, 524288, 262144);
  // fused qk^T -> softmax -> PV   (writes out_pre fp16 [b][l][h*64+d])
  attn_fused<<<dim3(32, 16, 4), 256, 0, stream>>>(qhf, kEb, vFtb, outp, 4096);
  // out = out_pre @ Wo + bo  (fp32)
  gemm_bt<128,128,64,64,0,1,1><<<dim3(128, 8, 1), 256, 0, stream>>>(
      outp, Wot, (void*)out, bo, nullptr, 16384, 1024, 1024, 1024, 1024, 1024, 1.f, 0, 0, 0);
  (void)in_sizes; (void)n_in; (void)out_size; (void)ws_size;
}